// Round 1
// baseline (10.863 us; speedup 1.0000x reference)
//
#include <hip/hip_runtime.h>

// GeneratorLoss: out = sum_{b,s} log(clip(pred[b,s,x[b,s]], 1e-20, 1)) * rewards[b,s]
// pred: (4, 2048, 50257) fp32; x: (4,2048) int; rewards: (4,2048) fp32; out: scalar fp32.
// Reference's one-hot/log over full vocab reduces mathematically to a gather:
// only 8192 scattered fp32 loads matter. Single-block latency-bound kernel.

#define BN 4
#define SN 2048
#define VN 50257
#define NTOK (BN * SN)   // 8192

__global__ __launch_bounds__(1024) void generator_loss_kernel(
    const float* __restrict__ pred,
    const int* __restrict__ x,
    const float* __restrict__ rewards,
    float* __restrict__ out) {
    const int tid = threadIdx.x;

    float local = 0.0f;
    // 8 tokens per thread; independent loads -> deep MLP to hide HBM latency.
    for (int i = tid; i < NTOK; i += 1024) {
        int t = x[i];
        float p = pred[(size_t)i * VN + (size_t)t];
        p = fminf(fmaxf(p, 1e-20f), 1.0f);
        local += __logf(p) * rewards[i];
    }

    // wave (64-lane) butterfly reduce
    #pragma unroll
    for (int off = 32; off > 0; off >>= 1)
        local += __shfl_down(local, off, 64);

    __shared__ float wave_sums[16];
    const int wave = tid >> 6;
    if ((tid & 63) == 0) wave_sums[wave] = local;
    __syncthreads();

    if (wave == 0) {
        float v = (tid < 16) ? wave_sums[tid] : 0.0f;
        #pragma unroll
        for (int off = 8; off > 0; off >>= 1)
            v += __shfl_down(v, off, 64);
        if (tid == 0) out[0] = v;
    }
}

extern "C" void kernel_launch(void* const* d_in, const int* in_sizes, int n_in,
                              void* d_out, int out_size, void* d_ws, size_t ws_size,
                              hipStream_t stream) {
    const float* pred    = (const float*)d_in[0];
    const int*   x       = (const int*)d_in[1];
    const float* rewards = (const float*)d_in[2];
    float* out = (float*)d_out;

    generator_loss_kernel<<<1, 1024, 0, stream>>>(pred, x, rewards, out);
}